// Round 8
// baseline (114.897 us; speedup 1.0000x reference)
//
#include <hip/hip_runtime.h>
#include <math.h>

// PRNN J2 plane-strain elastoplasticity scan.
// B=16384, T=128, F=3, MATPTS=16 (P=262144), O=3.
// R18: STORE-SCATTER PROBE on the R17 base (best: 53.8-54.5us profiled).
// Ledger: stall (~20us, ~40% of runtime) invariant under {2 waves, ILP-2,
// DPP-fence removal, LDS-reduce, store-drain separation, load distance,
// dispatch grain}. Only never-probed shared resource: the scattered global
// stores (8 insts/body x 24 lanes in 8x12B segments = 64 segment-touches
// per body on the CU's TA/TD, shared by both waves -> invariant under all
// wave/ILP probes). R18 keeps the VALU stream bit-identical and changes
// ONLY the store path:
//  * lanes 0-2 write folded outputs to a wave-private LDS slab (96B/group,
//    no barriers: within-wave DS is in-order; 2-way bank alias = free);
//  * lanes 0-5 read back one float4 slice and issue ONE
//    global_store_dwordx4 per body (48 lanes, 8x96B segments, 16 line
//    touches vs 64).
// Physics identical to R17 (deviatoric W1 rows, sqrt2-folded shear,
// g=fma(-Y,rq,1) yield, trace-free-p identity, eps-fold). Layout:
// 8 lanes/batch, 2 pts/lane (v2), 16 batches/block, 1024 blocks, 2 w/SIMD.

#define BLOCK 128
#define BPB 16              // batch elements per block (8 lanes each)
#define TSTEPS 128
#define ROWF (TSTEPS * 3)   // 384 floats per batch row

typedef float v2 __attribute__((ext_vector_type(2)));

static __device__ __forceinline__ v2 vfma(v2 a, v2 b, v2 c) {
    return __builtin_elementwise_fma(a, b, c);
}
static __device__ __forceinline__ v2 vmax(v2 a, v2 b) {
    return __builtin_elementwise_max(a, b);
}

// schedulable DPP add stage (init-only use)
#define DPP_ADDST(v, ctrl)                                                   \
    v += __int_as_float(__builtin_amdgcn_update_dpp(                         \
        0, __float_as_int(v), (ctrl), 0xf, 0xf, true))
// 8-lane butterfly: quad_perm xor1 (0xB1), xor2 (0x4E), row_half_mirror (0x141)
#define RED8(v)                                                              \
    do { DPP_ADDST(v, 0xB1); DPP_ADDST(v, 0x4E); DPP_ADDST(v, 0x141); } while (0)

// batched asm butterfly for the 24 in-loop partials
#define DPP_ST(r, ctrl) "v_add_f32_dpp %" #r ", %" #r ", %" #r " " ctrl \
                        " row_mask:0xf bank_mask:0xf\n\t"
#define DPP_STAGE24(ctrl) \
    DPP_ST(0, ctrl)  DPP_ST(1, ctrl)  DPP_ST(2, ctrl)  DPP_ST(3, ctrl)  \
    DPP_ST(4, ctrl)  DPP_ST(5, ctrl)  DPP_ST(6, ctrl)  DPP_ST(7, ctrl)  \
    DPP_ST(8, ctrl)  DPP_ST(9, ctrl)  DPP_ST(10, ctrl) DPP_ST(11, ctrl) \
    DPP_ST(12, ctrl) DPP_ST(13, ctrl) DPP_ST(14, ctrl) DPP_ST(15, ctrl) \
    DPP_ST(16, ctrl) DPP_ST(17, ctrl) DPP_ST(18, ctrl) DPP_ST(19, ctrl) \
    DPP_ST(20, ctrl) DPP_ST(21, ctrl) DPP_ST(22, ctrl) DPP_ST(23, ctrl)
#define DPP_BFLY24(a0,a1,a2,a3,a4,a5,a6,a7,a8,a9,a10,a11,                    \
                   a12,a13,a14,a15,a16,a17,a18,a19,a20,a21,a22,a23)          \
  asm volatile(                                                              \
    "s_nop 1\n\t"                                                            \
    DPP_STAGE24("quad_perm:[1,0,3,2]")                                       \
    DPP_STAGE24("quad_perm:[2,3,0,1]")                                       \
    DPP_STAGE24("row_half_mirror")                                           \
    : "+v"(a0), "+v"(a1), "+v"(a2), "+v"(a3), "+v"(a4), "+v"(a5),            \
      "+v"(a6), "+v"(a7), "+v"(a8), "+v"(a9), "+v"(a10), "+v"(a11),          \
      "+v"(a12), "+v"(a13), "+v"(a14), "+v"(a15), "+v"(a16), "+v"(a17),      \
      "+v"(a18), "+v"(a19), "+v"(a20), "+v"(a21), "+v"(a22), "+v"(a23))

__global__ __launch_bounds__(BLOCK, 2)
void prnn_j2_kernel(const float* __restrict__ x,
                    const float* __restrict__ W1,
                    const float* __restrict__ W2,
                    float* __restrict__ out)
{
    constexpr float MU    = (float)(3130.0 / (2.0 * (1.0 + 0.37)));
    constexpr float LAM   = (float)(3130.0 * 0.37 / ((1.0 + 0.37) * (1.0 - 2.0 * 0.37)));
    constexpr float SIG_Y = 64.8f;
    constexpr float H_ISO = 300.0f;
    const float TWO_MU  = 2.0f * MU;
    const float INV_DEN = 1.0f / (3.0f * MU + H_ISO);
    const float K3P     = (3.0f * MU) * INV_DEN;      // k = K3P * gm
    const float HP      = H_ISO * INV_DEN;            // Y += HP * fY
    const float CSC     = 1.0f / (MU * 2.4494897427831781f);  // 1/(MU*sqrt6)
    const float Y0      = SIG_Y * CSC;
    const float SQRT2   = 1.41421356237309515f;
    const float RSQRT2  = 0.70710678118654752f;

    // wave-private out-staging: [wave][group-in-wave][24 floats] = 1.5KB
    __shared__ float SBUF[2 * 8 * 24];

    const int tid = threadIdx.x;
    const int g   = tid >> 3;       // local batch 0..15
    const int l   = tid & 7;        // lane in 8-group; points (l, l+8)
    const int gb  = blockIdx.x * BPB + g;   // global batch
    const int wv  = tid >> 6;       // wave 0..1
    const int gw  = g & 7;          // group-in-wave 0..7
    const int sbase = wv * 192 + gw * 24;   // word base of this group's slab

    const float* xb = x + gb * ROWF;
    float* ob = out + gb * ROWF;

    // ---- packed per-thread weights: .x = point l, .y = point l+8 ----
    const int pa = l, pb = l + 8;
    v2 w1r0[3], w1r1[3], w1h2[3];      // raw row0, row1, half row2
    #pragma unroll
    for (int f = 0; f < 3; ++f) {
        w1r0[f].x = W1[(3 * pa + 0) * 3 + f];
        w1r0[f].y = W1[(3 * pb + 0) * 3 + f];
        w1r1[f].x = W1[(3 * pa + 1) * 3 + f];
        w1r1[f].y = W1[(3 * pb + 1) * 3 + f];
        w1h2[f].x = 0.5f * W1[(3 * pa + 2) * 3 + f];
        w1h2[f].y = 0.5f * W1[(3 * pb + 2) * 3 + f];
    }
    v2 w2p[3][3];
    #pragma unroll
    for (int o = 0; o < 3; ++o)
        #pragma unroll
        for (int c = 0; c < 3; ++c) {
            float wa = W2[o * 48 + 3 * pa + c];
            float wb = W2[o * 48 + 3 * pb + c];
            w2p[o][c].x = fmaxf(wa, 0.0f) + log1pf(expf(-fabsf(wa)));
            w2p[o][c].y = fmaxf(wb, 0.0f) + log1pf(expf(-fabsf(wb)));
        }

    // ---- constant elastic map M[o][f] = sum_p w2s_p . C . W1_p ----
    float Mrow[3];   // this lane's output-component row (l<3), else junk
    {
        float Ms[3][3];
        #pragma unroll
        for (int f = 0; f < 3; ++f) {
            v2 ax = (LAM + TWO_MU) * w1r0[f] + LAM * w1r1[f];
            v2 ay = LAM * w1r0[f] + (LAM + TWO_MU) * w1r1[f];
            v2 as = TWO_MU * w1h2[f];
            #pragma unroll
            for (int o = 0; o < 3; ++o) {
                v2 mp = vfma(w2p[o][0], ax, vfma(w2p[o][1], ay, w2p[o][2] * as));
                float ms = mp.x + mp.y;
                RED8(ms);               // sum over the 8 lanes (all 16 points)
                Ms[o][f] = ms;
            }
        }
        #pragma unroll
        for (int f = 0; f < 3; ++f) {
            float v = (l == 0) ? Ms[0][f] : ((l == 1) ? Ms[1][f] : Ms[2][f]);
            Mrow[f] = v;
        }
    }

    // ---- loop-form weights: deviatoric rows + sqrt2-folded shear ----
    v2 wdx[3], wdy[3], wsh[3];
    #pragma unroll
    for (int f = 0; f < 3; ++f) {
        wdx[f] = (2.0f * w1r0[f] - w1r1[f]) * (1.0f / 3.0f);  // ex0 = wdx.x
        wdy[f] = (2.0f * w1r1[f] - w1r0[f]) * (1.0f / 3.0f);  // ey0 = wdy.x
        wsh[f] = SQRT2 * w1h2[f];                              // exy2-elastic
    }
    #pragma unroll
    for (int o = 0; o < 3; ++o) w2p[o][2] *= RSQRT2;  // dps = sqrt2*dp3

    v2 p0 = {0.f,0.f}, p1 = {0.f,0.f}, ps = {0.f,0.f};
    v2 Y  = {Y0, Y0};
    v2 z0 = {0.f,0.f}, z1 = {0.f,0.f}, z2 = {0.f,0.f};

    const float4* xv = (const float4*)xb;   // group-uniform broadcast loads
    const bool wr3 = (l < 3);               // LDS producers
    const bool wr6 = (l < 6);               // coalesced storers

// Carry chain: p0 -> exd -> ua -> u -> rq -> gm -> k -> kdx -> p0.
// eps folded into innermost fma (u >= 1e-30 by construction; clamp deleted).
#define J2_PHYS(x0_, x1_, x2_, rr, mxv)                                      \
  {                                                                          \
    const float x0s = (x0_), x1s = (x1_), x2s = (x2_);                       \
    const v2 x0 = {x0s, x0s}, x1 = {x1s, x1s}, x2 = {x2s, x2s};              \
    const v2 ex0 = vfma(wdx[0], x0, vfma(wdx[1], x1, wdx[2] * x2));          \
    const v2 ey0 = vfma(wdy[0], x0, vfma(wdy[1], x1, wdy[2] * x2));          \
    const v2 wsy = vfma(wsh[0], x0, vfma(wsh[1], x1, wsh[2] * x2));          \
    const v2 exd = ex0 - p0;                                                 \
    const v2 eyd = ey0 - p1;                                                 \
    const v2 exy = wsy - ps;                                                 \
    const v2 szd = exd + eyd;           /* = -ezd, exact */                  \
    const v2 ua = vfma(eyd, eyd, vfma(exd, exd, (v2){1e-30f, 1e-30f}));      \
    const v2 ub = vfma(exy, exy, szd * szd);                                 \
    const v2 u = ua + ub;               /* >= 1e-30 by construction */       \
    v2 rq;                                                                   \
    rq.x = __builtin_amdgcn_rsqf(u.x);                                       \
    rq.y = __builtin_amdgcn_rsqf(u.y);                                       \
    const v2 gm = vmax(vfma(-Y, rq, (v2){1.0f, 1.0f}), (v2){0.0f, 0.0f});    \
    const v2 su = u * rq;               /* sqrt(u), Y side-chain only */     \
    const v2 k  = K3P * gm;                                                  \
    Y = vfma((v2){HP, HP}, gm * su, Y); /* fY = gm*su = max(su-Y,0) */       \
    const v2 kdx = k * exd;                                                  \
    const v2 kdy = k * eyd;                                                  \
    const v2 kdp = k * exy;                                                  \
    p0 += kdx;                                                               \
    p1 += kdy;                                                               \
    ps += kdp;                                                               \
    z0 = vfma(w2p[0][0], kdx, vfma(w2p[0][1], kdy, vfma(w2p[0][2], kdp, z0)));\
    z1 = vfma(w2p[1][0], kdx, vfma(w2p[1][1], kdy, vfma(w2p[1][2], kdp, z1)));\
    z2 = vfma(w2p[2][0], kdx, vfma(w2p[2][1], kdy, vfma(w2p[2][2], kdp, z2)));\
    (rr)[0] = z0.x + z0.y;                                                   \
    (rr)[1] = z1.x + z1.y;                                                   \
    (rr)[2] = z2.x + z2.y;                                                   \
    (mxv) = fmaf(Mrow[0], x0s, fmaf(Mrow[1], x1s, Mrow[2] * x2s));           \
  }

    float4 A0 = xv[0], A1 = xv[1], A2 = xv[2];
    float4 A3 = xv[3], A4 = xv[4], A5 = xv[5];

    for (int tb = 0; tb < TSTEPS / 8; ++tb) {
        // distance-1 prefetch; last iteration re-loads the same block (no OOB)
        const int nb = (tb < TSTEPS / 8 - 1) ? (6 * tb + 6) : (6 * tb);
        float4 An0 = xv[nb + 0];
        float4 An1 = xv[nb + 1];
        float4 An2 = xv[nb + 2];
        float4 An3 = xv[nb + 3];
        float4 An4 = xv[nb + 4];
        float4 An5 = xv[nb + 5];

        float r[24], mx[8];
        J2_PHYS(A0.x, A0.y, A0.z, r + 0,  mx[0]);
        J2_PHYS(A0.w, A1.x, A1.y, r + 3,  mx[1]);
        J2_PHYS(A1.z, A1.w, A2.x, r + 6,  mx[2]);
        J2_PHYS(A2.y, A2.z, A2.w, r + 9,  mx[3]);
        J2_PHYS(A3.x, A3.y, A3.z, r + 12, mx[4]);
        J2_PHYS(A3.w, A4.x, A4.y, r + 15, mx[5]);
        J2_PHYS(A4.z, A4.w, A5.x, r + 18, mx[6]);
        J2_PHYS(A5.y, A5.z, A5.w, r + 21, mx[7]);

        // sum the 24 cumulative-Z snapshots across the 8-lane group
        DPP_BFLY24(r[0],  r[1],  r[2],  r[3],  r[4],  r[5],
                   r[6],  r[7],  r[8],  r[9],  r[10], r[11],
                   r[12], r[13], r[14], r[15], r[16], r[17],
                   r[18], r[19], r[20], r[21], r[22], r[23]);

        // lane l (<3) folds component l into the wave-private LDS slab
        if (wr3) {
            #pragma unroll
            for (int s = 0; s < 8; ++s) {
                float zz = (l == 0) ? r[3*s] : ((l == 1) ? r[3*s+1] : r[3*s+2]);
                SBUF[sbase + 3 * s + l] = fmaf(-TWO_MU, zz, mx[s]);
            }
        }
        // lanes 0..5 read back a float4 slice; ONE coalesced dwordx4 store
        // (within-wave DS is in-order; no barrier needed, slab is wave-private)
        if (wr6) {
            const float4 v = *(const float4*)&SBUF[sbase + 4 * l];
            *(float4*)(ob + 24 * tb + 4 * l) = v;
        }

        A0 = An0; A1 = An1; A2 = An2;
        A3 = An3; A4 = An4; A5 = An5;
    }
#undef J2_PHYS
}

extern "C" void kernel_launch(void* const* d_in, const int* in_sizes, int n_in,
                              void* d_out, int out_size, void* d_ws, size_t ws_size,
                              hipStream_t stream) {
    const float* x  = (const float*)d_in[0];
    const float* W1 = (const float*)d_in[1];
    const float* W2 = (const float*)d_in[2];
    float* out = (float*)d_out;

    const int B = 16384;
    dim3 grid(B / BPB);   // 1024 blocks -> 4 blocks/CU, 2 waves/SIMD
    dim3 block(BLOCK);
    prnn_j2_kernel<<<grid, block, 0, stream>>>(x, W1, W2, out);
}

// Round 9
// 113.127 us; speedup vs baseline: 1.0156x; 1.0156x over previous
//
#include <hip/hip_runtime.h>
#include <math.h>

// PRNN J2 plane-strain elastoplasticity scan.
// B=16384, T=128, F=3, MATPTS=16 (P=262144), O=3.
// R19: TRANSFORMED-BASIS recursion on the R17 base (best: 53.8us profiled).
// Ledger: every structural probe null (waves/ILP/fences/LDS/stores/loads);
// only instruction DELETION converts (~0.5x). R19 deletes the z-accumulator
// block (9 pk-fma/step = ~20% of loop issue) via the identity
//   z_o(t) = sum_steps w2p[o].kd = w2p[o].p(t)  (kd are p's increments)
// by running the recursion in the transformed basis p~ = W.p:
//  * V = W.W1_dev precomputed -> e~0 = V.x (same 9 fma as before);
//  * e~d = e~0 - p~ (3); p~ += k.e~d (3, was kd+p = 6); z-update GONE;
//    r[o] = p~_o.x + p~_o.y directly.
//  * u through the congruent form u = e~d^T G e~d, G = W^-T Q W^-1
//    (Q = [[2,1,0],[1,2,0],[0,0,1]] folded basis), G precomputed at init
//    via 3x3 cofactor inverse: 10 ops vs 6 (+4). Net -17% loop issue.
//  * max(u,1e-30) clamp kept: guards rsq against cancellation-negative u.
// Store path = R17 direct predicated stores (R18 LDS staging reverted, +1us).
// Physics otherwise R17 (deviatoric W1 rows, sqrt2-folded shear,
// g=fma(-Y,rq,1) yield). Layout: 8 lanes/batch, 2 pts/lane (v2),
// 16 batches/block, 1024 blocks, 2 waves/SIMD.

#define BLOCK 128
#define BPB 16              // batch elements per block (8 lanes each)
#define TSTEPS 128
#define ROWF (TSTEPS * 3)   // 384 floats per batch row

typedef float v2 __attribute__((ext_vector_type(2)));

static __device__ __forceinline__ v2 vfma(v2 a, v2 b, v2 c) {
    return __builtin_elementwise_fma(a, b, c);
}
static __device__ __forceinline__ v2 vmax(v2 a, v2 b) {
    return __builtin_elementwise_max(a, b);
}

// schedulable DPP add stage (init-only use)
#define DPP_ADDST(v, ctrl)                                                   \
    v += __int_as_float(__builtin_amdgcn_update_dpp(                         \
        0, __float_as_int(v), (ctrl), 0xf, 0xf, true))
// 8-lane butterfly: quad_perm xor1 (0xB1), xor2 (0x4E), row_half_mirror (0x141)
#define RED8(v)                                                              \
    do { DPP_ADDST(v, 0xB1); DPP_ADDST(v, 0x4E); DPP_ADDST(v, 0x141); } while (0)

// batched asm butterfly for the 24 in-loop partials
#define DPP_ST(r, ctrl) "v_add_f32_dpp %" #r ", %" #r ", %" #r " " ctrl \
                        " row_mask:0xf bank_mask:0xf\n\t"
#define DPP_STAGE24(ctrl) \
    DPP_ST(0, ctrl)  DPP_ST(1, ctrl)  DPP_ST(2, ctrl)  DPP_ST(3, ctrl)  \
    DPP_ST(4, ctrl)  DPP_ST(5, ctrl)  DPP_ST(6, ctrl)  DPP_ST(7, ctrl)  \
    DPP_ST(8, ctrl)  DPP_ST(9, ctrl)  DPP_ST(10, ctrl) DPP_ST(11, ctrl) \
    DPP_ST(12, ctrl) DPP_ST(13, ctrl) DPP_ST(14, ctrl) DPP_ST(15, ctrl) \
    DPP_ST(16, ctrl) DPP_ST(17, ctrl) DPP_ST(18, ctrl) DPP_ST(19, ctrl) \
    DPP_ST(20, ctrl) DPP_ST(21, ctrl) DPP_ST(22, ctrl) DPP_ST(23, ctrl)
#define DPP_BFLY24(a0,a1,a2,a3,a4,a5,a6,a7,a8,a9,a10,a11,                    \
                   a12,a13,a14,a15,a16,a17,a18,a19,a20,a21,a22,a23)          \
  asm volatile(                                                              \
    "s_nop 1\n\t"                                                            \
    DPP_STAGE24("quad_perm:[1,0,3,2]")                                       \
    DPP_STAGE24("quad_perm:[2,3,0,1]")                                       \
    DPP_STAGE24("row_half_mirror")                                           \
    : "+v"(a0), "+v"(a1), "+v"(a2), "+v"(a3), "+v"(a4), "+v"(a5),            \
      "+v"(a6), "+v"(a7), "+v"(a8), "+v"(a9), "+v"(a10), "+v"(a11),          \
      "+v"(a12), "+v"(a13), "+v"(a14), "+v"(a15), "+v"(a16), "+v"(a17),      \
      "+v"(a18), "+v"(a19), "+v"(a20), "+v"(a21), "+v"(a22), "+v"(a23))

__global__ __launch_bounds__(BLOCK, 2)
void prnn_j2_kernel(const float* __restrict__ x,
                    const float* __restrict__ W1,
                    const float* __restrict__ W2,
                    float* __restrict__ out)
{
    constexpr float MU    = (float)(3130.0 / (2.0 * (1.0 + 0.37)));
    constexpr float LAM   = (float)(3130.0 * 0.37 / ((1.0 + 0.37) * (1.0 - 2.0 * 0.37)));
    constexpr float SIG_Y = 64.8f;
    constexpr float H_ISO = 300.0f;
    const float TWO_MU  = 2.0f * MU;
    const float INV_DEN = 1.0f / (3.0f * MU + H_ISO);
    const float K3P     = (3.0f * MU) * INV_DEN;      // k = K3P * gm
    const float HP      = H_ISO * INV_DEN;            // Y += HP * fY
    const float CSC     = 1.0f / (MU * 2.4494897427831781f);  // 1/(MU*sqrt6)
    const float Y0      = SIG_Y * CSC;
    const float SQRT2   = 1.41421356237309515f;
    const float RSQRT2  = 0.70710678118654752f;

    const int tid = threadIdx.x;
    const int g   = tid >> 3;       // local batch 0..15
    const int l   = tid & 7;        // lane in 8-group; points (l, l+8)
    const int gb  = blockIdx.x * BPB + g;   // global batch

    const float* xb = x + gb * ROWF;
    float* ob = out + gb * ROWF;

    // ---- packed per-thread weights: .x = point l, .y = point l+8 ----
    const int pa = l, pb = l + 8;
    v2 w1r0[3], w1r1[3], w1h2[3];      // raw row0, row1, half row2
    #pragma unroll
    for (int f = 0; f < 3; ++f) {
        w1r0[f].x = W1[(3 * pa + 0) * 3 + f];
        w1r0[f].y = W1[(3 * pb + 0) * 3 + f];
        w1r1[f].x = W1[(3 * pa + 1) * 3 + f];
        w1r1[f].y = W1[(3 * pb + 1) * 3 + f];
        w1h2[f].x = 0.5f * W1[(3 * pa + 2) * 3 + f];
        w1h2[f].y = 0.5f * W1[(3 * pb + 2) * 3 + f];
    }
    v2 w2p[3][3];
    #pragma unroll
    for (int o = 0; o < 3; ++o)
        #pragma unroll
        for (int c = 0; c < 3; ++c) {
            float wa = W2[o * 48 + 3 * pa + c];
            float wb = W2[o * 48 + 3 * pb + c];
            w2p[o][c].x = fmaxf(wa, 0.0f) + log1pf(expf(-fabsf(wa)));
            w2p[o][c].y = fmaxf(wb, 0.0f) + log1pf(expf(-fabsf(wb)));
        }

    // ---- constant elastic map M[o][f] = sum_p w2s_p . C . W1_p ----
    float Mrow[3];   // this lane's output-component row (l<3), else junk
    {
        float Ms[3][3];
        #pragma unroll
        for (int f = 0; f < 3; ++f) {
            v2 ax = (LAM + TWO_MU) * w1r0[f] + LAM * w1r1[f];
            v2 ay = LAM * w1r0[f] + (LAM + TWO_MU) * w1r1[f];
            v2 as = TWO_MU * w1h2[f];
            #pragma unroll
            for (int o = 0; o < 3; ++o) {
                v2 mp = vfma(w2p[o][0], ax, vfma(w2p[o][1], ay, w2p[o][2] * as));
                float ms = mp.x + mp.y;
                RED8(ms);               // sum over the 8 lanes (all 16 points)
                Ms[o][f] = ms;
            }
        }
        #pragma unroll
        for (int f = 0; f < 3; ++f) {
            float v = (l == 0) ? Ms[0][f] : ((l == 1) ? Ms[1][f] : Ms[2][f]);
            Mrow[f] = v;
        }
    }

    // ---- deviatoric rows + sqrt2-folded shear (physical basis) ----
    v2 wdx[3], wdy[3], wsh[3];
    #pragma unroll
    for (int f = 0; f < 3; ++f) {
        wdx[f] = (2.0f * w1r0[f] - w1r1[f]) * (1.0f / 3.0f);  // ex0 = wdx.x
        wdy[f] = (2.0f * w1r1[f] - w1r0[f]) * (1.0f / 3.0f);  // ey0 = wdy.x
        wsh[f] = SQRT2 * w1h2[f];                              // exy2-elastic
    }
    #pragma unroll
    for (int o = 0; o < 3; ++o) w2p[o][2] *= RSQRT2;  // folded W: p~ = W.(p0,p1,ps)

    // ---- transformed-basis constants ----
    // V[o][f] = W[o] . (wdx,wdy,wsh)[.,f]   (e~0 = V.x)
    v2 V[3][3];
    #pragma unroll
    for (int o = 0; o < 3; ++o)
        #pragma unroll
        for (int f = 0; f < 3; ++f)
            V[o][f] = vfma(w2p[o][0], wdx[f],
                      vfma(w2p[o][1], wdy[f], w2p[o][2] * wsh[f]));

    // A = W^-1 via cofactors; G = A^T Q A with Q=[[2,1,0],[1,2,0],[0,0,1]].
    v2 G00, G11, G22, TG01, TG02, TG12;
    {
        v2 A[3][3];
        const v2 c00 = w2p[1][1]*w2p[2][2] - w2p[1][2]*w2p[2][1];
        const v2 c01 = w2p[1][0]*w2p[2][2] - w2p[1][2]*w2p[2][0];
        const v2 c02 = w2p[1][0]*w2p[2][1] - w2p[1][1]*w2p[2][0];
        const v2 det = w2p[0][0]*c00 - w2p[0][1]*c01 + w2p[0][2]*c02;
        const v2 rd  = (v2){1.0f, 1.0f} / det;
        A[0][0] =  c00 * rd;
        A[0][1] = (w2p[0][2]*w2p[2][1] - w2p[0][1]*w2p[2][2]) * rd;
        A[0][2] = (w2p[0][1]*w2p[1][2] - w2p[0][2]*w2p[1][1]) * rd;
        A[1][0] = -c01 * rd;
        A[1][1] = (w2p[0][0]*w2p[2][2] - w2p[0][2]*w2p[2][0]) * rd;
        A[1][2] = (w2p[0][2]*w2p[1][0] - w2p[0][0]*w2p[1][2]) * rd;
        A[2][0] =  c02 * rd;
        A[2][1] = (w2p[0][1]*w2p[2][0] - w2p[0][0]*w2p[2][1]) * rd;
        A[2][2] = (w2p[0][0]*w2p[1][1] - w2p[0][1]*w2p[1][0]) * rd;
        // G_ij = 2(A0i A0j + A1i A1j) + (A0i A1j + A1i A0j) + A2i A2j
        #define GFORM(i, j)                                                  \
            (2.0f*(A[0][i]*A[0][j] + A[1][i]*A[1][j])                        \
             + (A[0][i]*A[1][j] + A[1][i]*A[0][j])                           \
             + A[2][i]*A[2][j])
        G00 = GFORM(0, 0);
        G11 = GFORM(1, 1);
        G22 = GFORM(2, 2);
        TG01 = 2.0f * GFORM(0, 1);
        TG02 = 2.0f * GFORM(0, 2);
        TG12 = 2.0f * GFORM(1, 2);
        #undef GFORM
    }

    v2 q0 = {0.f,0.f}, q1 = {0.f,0.f}, q2 = {0.f,0.f};   // p~ state
    v2 Y  = {Y0, Y0};

    const float4* xv = (const float4*)xb;   // group-uniform broadcast loads
    const bool wact = (l < 3);
    float* obl = ob + l;

// Carry chain: q -> e~d -> quadratic(3) -> u -> rq -> gm -> k -> q.
// r[o] = q_o.x + q_o.y is the cumulative Z directly (z == W.p == p~).
#define J2_PHYS(x0_, x1_, x2_, rr, mxv)                                      \
  {                                                                          \
    const float x0s = (x0_), x1s = (x1_), x2s = (x2_);                       \
    const v2 x0 = {x0s, x0s}, x1 = {x1s, x1s}, x2 = {x2s, x2s};              \
    const v2 e0 = vfma(V[0][0], x0, vfma(V[0][1], x1, V[0][2] * x2));        \
    const v2 e1 = vfma(V[1][0], x0, vfma(V[1][1], x1, V[1][2] * x2));        \
    const v2 e2 = vfma(V[2][0], x0, vfma(V[2][1], x1, V[2][2] * x2));        \
    const v2 a = e0 - q0;                                                    \
    const v2 b = e1 - q1;                                                    \
    const v2 c = e2 - q2;                                                    \
    const v2 h0 = vfma(G00, a, vfma(TG01, b, TG02 * c));                     \
    const v2 h1 = vfma(G11, b, TG12 * c);                                    \
    const v2 cc = c * c;                                                     \
    v2 u = vfma(h0, a, vfma(h1, b, G22 * cc));                               \
    u = vmax(u, (v2){1e-30f, 1e-30f});  /* guards rsq vs cancellation */     \
    v2 rq;                                                                   \
    rq.x = __builtin_amdgcn_rsqf(u.x);                                       \
    rq.y = __builtin_amdgcn_rsqf(u.y);                                       \
    const v2 gm = vmax(vfma(-Y, rq, (v2){1.0f, 1.0f}), (v2){0.0f, 0.0f});    \
    const v2 su = u * rq;               /* sqrt(u), Y side-chain only */     \
    const v2 k  = K3P * gm;                                                  \
    Y = vfma((v2){HP, HP}, gm * su, Y); /* fY = gm*su = max(su-Y,0) */       \
    q0 = vfma(k, a, q0);                                                     \
    q1 = vfma(k, b, q1);                                                     \
    q2 = vfma(k, c, q2);                                                     \
    (rr)[0] = q0.x + q0.y;                                                   \
    (rr)[1] = q1.x + q1.y;                                                   \
    (rr)[2] = q2.x + q2.y;                                                   \
    (mxv) = fmaf(Mrow[0], x0s, fmaf(Mrow[1], x1s, Mrow[2] * x2s));           \
  }

    float4 A0 = xv[0], A1 = xv[1], A2 = xv[2];
    float4 A3 = xv[3], A4 = xv[4], A5 = xv[5];

    for (int tb = 0; tb < TSTEPS / 8; ++tb) {
        // distance-1 prefetch; last iteration re-loads the same block (no OOB)
        const int nb = (tb < TSTEPS / 8 - 1) ? (6 * tb + 6) : (6 * tb);
        float4 An0 = xv[nb + 0];
        float4 An1 = xv[nb + 1];
        float4 An2 = xv[nb + 2];
        float4 An3 = xv[nb + 3];
        float4 An4 = xv[nb + 4];
        float4 An5 = xv[nb + 5];

        float r[24], mx[8];
        J2_PHYS(A0.x, A0.y, A0.z, r + 0,  mx[0]);
        J2_PHYS(A0.w, A1.x, A1.y, r + 3,  mx[1]);
        J2_PHYS(A1.z, A1.w, A2.x, r + 6,  mx[2]);
        J2_PHYS(A2.y, A2.z, A2.w, r + 9,  mx[3]);
        J2_PHYS(A3.x, A3.y, A3.z, r + 12, mx[4]);
        J2_PHYS(A3.w, A4.x, A4.y, r + 15, mx[5]);
        J2_PHYS(A4.z, A4.w, A5.x, r + 18, mx[6]);
        J2_PHYS(A5.y, A5.z, A5.w, r + 21, mx[7]);

        // sum the 24 cumulative-Z snapshots across the 8-lane group
        DPP_BFLY24(r[0],  r[1],  r[2],  r[3],  r[4],  r[5],
                   r[6],  r[7],  r[8],  r[9],  r[10], r[11],
                   r[12], r[13], r[14], r[15], r[16], r[17],
                   r[18], r[19], r[20], r[21], r[22], r[23]);

        if (wact) {
            // lane l writes component l: out = M.x - 2MU * Z
            #pragma unroll
            for (int s = 0; s < 8; ++s) {
                float zz = (l == 0) ? r[3*s] : ((l == 1) ? r[3*s+1] : r[3*s+2]);
                obl[24 * tb + 3 * s] = fmaf(-TWO_MU, zz, mx[s]);
            }
        }

        A0 = An0; A1 = An1; A2 = An2;
        A3 = An3; A4 = An4; A5 = An5;
    }
#undef J2_PHYS
}

extern "C" void kernel_launch(void* const* d_in, const int* in_sizes, int n_in,
                              void* d_out, int out_size, void* d_ws, size_t ws_size,
                              hipStream_t stream) {
    const float* x  = (const float*)d_in[0];
    const float* W1 = (const float*)d_in[1];
    const float* W2 = (const float*)d_in[2];
    float* out = (float*)d_out;

    const int B = 16384;
    dim3 grid(B / BPB);   // 1024 blocks -> 4 blocks/CU, 2 waves/SIMD
    dim3 block(BLOCK);
    prnn_j2_kernel<<<grid, block, 0, stream>>>(x, W1, W2, out);
}